// Round 8
// baseline (428.640 us; speedup 1.0000x reference)
//
#include <hip/hip_runtime.h>
#include <hip/hip_bf16.h>

#define NEG_SLOPE 0.2f
#define G_SHIFT 7
#define GSZ 128          // nodes per bucket
#define CHUNK 4096       // edges per coarse block; also per-bucket region capacity

// ---------- fused kernel 1: coarse edge-bucketing (blocks < NCH) and
// layer-1 GEMM + el/er epilogue (remaining blocks). Independent work. -------
union K1Smem {
    struct { float xs[32][68]; float ws[32][128]; } g;                 // 25088 B
    struct { int hist[800]; int lbase[800]; int gbase[800];
             unsigned stage[CHUNK]; } c;                               // 25984 B
};

__global__ __launch_bounds__(256) void k1_fused(
    const int* __restrict__ src, const int* __restrict__ dst,
    int* __restrict__ gcursor, unsigned* __restrict__ inter, int NB, int E,
    int NCH,
    const float* __restrict__ x, const float* __restrict__ W,
    const float* __restrict__ al, const float* __restrict__ ar,
    __hip_bfloat16* __restrict__ outb, float* __restrict__ el,
    float* __restrict__ er, int N) {
    __shared__ K1Smem sm;
    const int tid = threadIdx.x;

    if ((int)blockIdx.x < NCH) {
        // ================= coarse scatter =================
        const int e0 = blockIdx.x * CHUNK;
        const int cnt = min(CHUNK, E - e0);

        for (int i = tid; i < NB; i += 256) sm.c.hist[i] = 0;
        __syncthreads();

        unsigned pk[16];
        int bb[16];
#pragma unroll
        for (int r = 0; r < 16; ++r) {
            int idx = tid + r * 256;
            if (idx < cnt) {
                int s = src[e0 + idx];
                int d = dst[e0 + idx];
                pk[r] = ((unsigned)s << G_SHIFT) | (unsigned)(d & (GSZ - 1));
                bb[r] = d >> G_SHIFT;
                atomicAdd(&sm.c.hist[bb[r]], 1);
            }
        }
        __syncthreads();
        if (tid < 64) {
            int carry = 0;
            for (int i = 0; i < NB; i += 64) {
                int v = (i + tid < NB) ? sm.c.hist[i + tid] : 0;
                int xv = v;
                for (int o = 1; o < 64; o <<= 1) {
                    int tt = __shfl_up(xv, o, 64);
                    if (tid >= o) xv += tt;
                }
                if (i + tid < NB) sm.c.lbase[i + tid] = carry + xv - v;
                carry += __shfl(xv, 63, 64);
            }
        }
        __syncthreads();
        for (int i = tid; i < NB; i += 256) {
            int hh = sm.c.hist[i];
            sm.c.gbase[i] = (hh > 0) ? (i * CHUNK + atomicAdd(&gcursor[i], hh)) : 0;
        }
        __syncthreads();
        for (int i = tid; i < NB; i += 256) sm.c.hist[i] = 0;
        __syncthreads();
#pragma unroll
        for (int r = 0; r < 16; ++r) {
            int idx = tid + r * 256;
            if (idx < cnt) {
                int b = bb[r];
                int rk = atomicAdd(&sm.c.hist[b], 1);
                sm.c.stage[sm.c.lbase[b] + rk] = pk[r];
            }
        }
        __syncthreads();
#pragma unroll
        for (int r = 0; r < 16; ++r) {
            int idx = tid + r * 256;
            if (idx < cnt) {
                unsigned ed = sm.c.stage[idx];
                // recover bucket: find b such that lbase[b] <= idx < lbase[b+1]
                // cheaper: recompute from staged order — we stored by bucket, so
                // use dst bucket from the packed record's position via gbase map.
                // Instead: rescan original record's bucket from pk/bb is lost;
                // recover from the staged value's local node + binary search is
                // overkill — carry bucket in upper bits is impossible (24 used).
                // So: we re-derive by binary search over lbase.
                int lo = 0, hi = NB - 1;
                while (lo < hi) {
                    int mid = (lo + hi + 1) >> 1;
                    if (sm.c.lbase[mid] <= idx) lo = mid; else hi = mid - 1;
                }
                inter[sm.c.gbase[lo] + (idx - sm.c.lbase[lo])] = ed;
            }
        }
    } else {
        // ================= gemm1 + fused el/er =================
        const int K = 128, C = 128, BM = 64, BK = 32;
        const int t = tid;
        const int trow = t >> 4;
        const int tcol = t & 15;
        const int m0 = ((int)blockIdx.x - NCH) * BM;

        float acc[4][8];
#pragma unroll
        for (int i = 0; i < 4; ++i)
#pragma unroll
            for (int j = 0; j < 8; ++j) acc[i][j] = 0.f;

        for (int k0 = 0; k0 < K; k0 += BK) {
            {
                const float4* W4 = (const float4*)(W + k0 * C);
#pragma unroll
                for (int r = 0; r < 4; ++r) {
                    int q = t + 256 * r;
                    int k = q >> 5;
                    int c4 = q & 31;
                    float4 v = W4[k * 32 + c4];
                    *((float4*)&sm.g.ws[k][c4 * 4]) = v;
                }
            }
            {
#pragma unroll
                for (int r = 0; r < 2; ++r) {
                    int q = t + 256 * r;
                    int m = q >> 3;
                    int k4 = q & 7;
                    int gm = m0 + m;
                    if (gm >= N) gm = N - 1;
                    float4 v = *((const float4*)(x + (size_t)gm * K + k0 + k4 * 4));
                    sm.g.xs[k4 * 4 + 0][m] = v.x;
                    sm.g.xs[k4 * 4 + 1][m] = v.y;
                    sm.g.xs[k4 * 4 + 2][m] = v.z;
                    sm.g.xs[k4 * 4 + 3][m] = v.w;
                }
            }
            __syncthreads();

#pragma unroll
            for (int k = 0; k < BK; ++k) {
                float4 a = *((const float4*)&sm.g.xs[k][trow * 4]);
                float4 b0 = *((const float4*)&sm.g.ws[k][tcol * 8]);
                float4 b1 = *((const float4*)&sm.g.ws[k][tcol * 8 + 4]);
                float av[4] = {a.x, a.y, a.z, a.w};
                float bv[8] = {b0.x, b0.y, b0.z, b0.w, b1.x, b1.y, b1.z, b1.w};
#pragma unroll
                for (int i = 0; i < 4; ++i)
#pragma unroll
                    for (int j = 0; j < 8; ++j) acc[i][j] += av[i] * bv[j];
            }
            __syncthreads();
        }

        const int h = tcol >> 2;
        const int d0 = (tcol & 3) * 8;
        float alv[8], arv[8];
#pragma unroll
        for (int j = 0; j < 8; ++j) {
            alv[j] = al[h * 32 + d0 + j];
            arv[j] = ar[h * 32 + d0 + j];
        }
#pragma unroll
        for (int i = 0; i < 4; ++i) {
            int gm = m0 + trow * 4 + i;
            if (gm < N) {
                union { __hip_bfloat16 hh[8]; uint4 u; } pkk;
#pragma unroll
                for (int j = 0; j < 8; ++j) pkk.hh[j] = __float2bfloat16(acc[i][j]);
                *((uint4*)(outb + (size_t)gm * 128 + tcol * 8)) = pkk.u;
            }
            float pl = 0.f, pr = 0.f;
#pragma unroll
            for (int j = 0; j < 8; ++j) {
                pl += acc[i][j] * alv[j];
                pr += acc[i][j] * arv[j];
            }
            pl += __shfl_xor(pl, 1); pl += __shfl_xor(pl, 2);
            pr += __shfl_xor(pr, 1); pr += __shfl_xor(pr, 2);
            if ((tcol & 3) == 0 && gm < N) {
                el[gm * 4 + h] = pl;
                er[gm * 4 + h] = pr;
            }
        }
    }
}

// ---------- fine scatter: per-bucket CSR finalize (self-computed base) ------
__global__ __launch_bounds__(256) void fine_scatter(
    const unsigned* __restrict__ inter, const int* __restrict__ gcursor,
    int* __restrict__ deg, int* __restrict__ rowptr, int* __restrict__ esrc,
    int N, int NB) {
    __shared__ int h[GSZ];
    __shared__ int lb[GSZ];
    __shared__ int stage[CHUNK];
    const int b = blockIdx.x;
    const int tid = threadIdx.x;
    const int cnt = gcursor[b];
    const unsigned* ep = inter + (size_t)b * CHUNK;

    // bucket base = sum gcursor[0..b) using stage as scratch
    {
        int s = 0;
        for (int i = tid; i < b; i += 256) s += gcursor[i];
        stage[tid] = s;
        __syncthreads();
        for (int o = 128; o > 0; o >>= 1) {
            if (tid < o) stage[tid] += stage[tid + o];
            __syncthreads();
        }
    }
    const int base = stage[0];
    __syncthreads();

    if (tid < GSZ) h[tid] = 0;
    __syncthreads();

    int ss[16];
    unsigned char ln[16];
    int nr = 0;
    for (int idx = tid; idx < cnt; idx += 256) {
        unsigned ed = ep[idx];
        ss[nr] = (int)(ed >> G_SHIFT);
        int l = (int)(ed & (GSZ - 1));
        ln[nr++] = (unsigned char)l;
        atomicAdd(&h[l], 1);
    }
    __syncthreads();
    if (tid < 64) {
        int carry = 0;
        for (int i = 0; i < GSZ; i += 64) {
            int v = h[i + tid];
            int xv = v;
            for (int o = 1; o < 64; o <<= 1) {
                int tt = __shfl_up(xv, o, 64);
                if (tid >= o) xv += tt;
            }
            lb[i + tid] = carry + xv - v;
            carry += __shfl(xv, 63, 64);
        }
    }
    __syncthreads();
    if (tid < GSZ) {
        int node = b * GSZ + tid;
        if (node < N) {
            deg[node] = h[tid];
            rowptr[node] = base + lb[tid];
        }
        h[tid] = 0;
    }
    __syncthreads();
    for (int r = 0; r < nr; ++r) {
        int l = ln[r];
        int rk = atomicAdd(&h[l], 1);
        stage[lb[l] + rk] = ss[r];
    }
    __syncthreads();
    for (int idx = tid; idx < cnt; idx += 256) esrc[base + idx] = stage[idx];
}

__device__ __forceinline__ float bf2f(unsigned short v) {
    return __uint_as_float((unsigned)v << 16);
}

// ---------- layer-1 pull: 32 lanes/node, 4 heads, bf16 feat, 8x MLP ---------
__global__ __launch_bounds__(256) void pull1_kernel(
    const int* __restrict__ rowptr, const int* __restrict__ deg,
    const int* __restrict__ esrc, const float* __restrict__ el,
    const float* __restrict__ er, const __hip_bfloat16* __restrict__ featb,
    const float* __restrict__ b, float* __restrict__ hbuf, int N) {
    int tid = blockIdx.x * 256 + threadIdx.x;
    int node = tid >> 5;
    int lane = threadIdx.x & 31;
    int h = lane >> 3;
    int d4 = lane & 7;
    if (node >= N) return;

    int start = rowptr[node];
    int cnt = deg[node];
    float er_nh = er[node * 4 + h];
    const int* ep = esrc + start;
    const unsigned short* fb = (const unsigned short*)featb + h * 32 + d4 * 4;

    float4 acc = make_float4(0.f, 0.f, 0.f, 0.f);
    float sumex = 0.f;

    int i = 0;
    for (; i + 8 <= cnt; i += 8) {
        int s[8];
#pragma unroll
        for (int j = 0; j < 8; ++j) s[j] = ep[i + j];
        float ee[8];
        ushort4 uu[8];
#pragma unroll
        for (int j = 0; j < 8; ++j) {
            ee[j] = el[s[j] * 4 + h];
            uu[j] = *((const ushort4*)(fb + (size_t)s[j] * 128));
        }
#pragma unroll
        for (int j = 0; j < 8; ++j) {
            float v = ee[j] + er_nh;
            v = v > 0.f ? v : NEG_SLOPE * v;
            float ex = __expf(v);
            acc.x += ex * bf2f(uu[j].x);
            acc.y += ex * bf2f(uu[j].y);
            acc.z += ex * bf2f(uu[j].z);
            acc.w += ex * bf2f(uu[j].w);
            sumex += ex;
        }
    }
    for (; i + 4 <= cnt; i += 4) {
        int s[4];
#pragma unroll
        for (int j = 0; j < 4; ++j) s[j] = ep[i + j];
        float ee[4];
        ushort4 uu[4];
#pragma unroll
        for (int j = 0; j < 4; ++j) {
            ee[j] = el[s[j] * 4 + h];
            uu[j] = *((const ushort4*)(fb + (size_t)s[j] * 128));
        }
#pragma unroll
        for (int j = 0; j < 4; ++j) {
            float v = ee[j] + er_nh;
            v = v > 0.f ? v : NEG_SLOPE * v;
            float ex = __expf(v);
            acc.x += ex * bf2f(uu[j].x);
            acc.y += ex * bf2f(uu[j].y);
            acc.z += ex * bf2f(uu[j].z);
            acc.w += ex * bf2f(uu[j].w);
            sumex += ex;
        }
    }
    for (; i < cnt; ++i) {
        int s = ep[i];
        float v = el[s * 4 + h] + er_nh;
        v = v > 0.f ? v : NEG_SLOPE * v;
        float ex = __expf(v);
        ushort4 u = *((const ushort4*)(fb + (size_t)s * 128));
        acc.x += ex * bf2f(u.x);
        acc.y += ex * bf2f(u.y);
        acc.z += ex * bf2f(u.z);
        acc.w += ex * bf2f(u.w);
        sumex += ex;
    }
    float inv = 1.f / ((sumex == 0.f) ? 1.f : sumex);
    float4 bb = *((const float4*)(b + h * 32 + d4 * 4));
    float4 o;
    o.x = acc.x * inv + bb.x;
    o.y = acc.y * inv + bb.y;
    o.z = acc.z * inv + bb.z;
    o.w = acc.w * inv + bb.w;
    o.x += __shfl_xor(o.x, 8); o.x += __shfl_xor(o.x, 16);
    o.y += __shfl_xor(o.y, 8); o.y += __shfl_xor(o.y, 16);
    o.z += __shfl_xor(o.z, 8); o.z += __shfl_xor(o.z, 16);
    o.w += __shfl_xor(o.w, 8); o.w += __shfl_xor(o.w, 16);
    if (h == 0) {
        o.x = fmaxf(o.x * 0.25f, 0.f);
        o.y = fmaxf(o.y * 0.25f, 0.f);
        o.z = fmaxf(o.z * 0.25f, 0.f);
        o.w = fmaxf(o.w * 0.25f, 0.f);
        *((float4*)(hbuf + (size_t)node * 32 + d4 * 4)) = o;
    }
}

// ---------- layer-2 GEMM (K=32, C=16) + fused el/er (H=1) ----------
__global__ __launch_bounds__(256) void gemm2_fused(
    const float* __restrict__ x, const float* __restrict__ W,
    const float* __restrict__ al, const float* __restrict__ ar,
    float* __restrict__ out, float* __restrict__ el, float* __restrict__ er,
    int N) {
    const int K = 32, C = 16;
    int idx = blockIdx.x * blockDim.x + threadIdx.x;
    if (idx >= N * C) return;
    int n = idx / C, c = idx % C;
    const float* xr = x + (size_t)n * K;
    float acc = 0.f;
#pragma unroll
    for (int k = 0; k < K; ++k) acc += xr[k] * W[k * C + c];
    out[idx] = acc;
    float pl = acc * al[c];
    float pr = acc * ar[c];
    pl += __shfl_xor(pl, 1); pl += __shfl_xor(pl, 2);
    pl += __shfl_xor(pl, 4); pl += __shfl_xor(pl, 8);
    pr += __shfl_xor(pr, 1); pr += __shfl_xor(pr, 2);
    pr += __shfl_xor(pr, 4); pr += __shfl_xor(pr, 8);
    if (c == 0) {
        el[n] = pl;
        er[n] = pr;
    }
}

// ---------- layer-2 pull: 4 lanes/node (H=1, D=16), fp32 feat, 8x MLP -------
__global__ __launch_bounds__(256) void pull2_kernel(
    const int* __restrict__ rowptr, const int* __restrict__ deg,
    const int* __restrict__ esrc, const float* __restrict__ el,
    const float* __restrict__ er, const float* __restrict__ feat,
    const float* __restrict__ b, float* __restrict__ outp, int N) {
    int tid = blockIdx.x * 256 + threadIdx.x;
    int node = tid >> 2;
    int d4 = threadIdx.x & 3;
    if (node >= N) return;

    int start = rowptr[node];
    int cnt = deg[node];
    float er_n = er[node];
    const int* ep = esrc + start;
    const float* fb = feat + d4 * 4;

    float4 acc = make_float4(0.f, 0.f, 0.f, 0.f);
    float sumex = 0.f;
    int i = 0;
    for (; i + 8 <= cnt; i += 8) {
        int s[8];
#pragma unroll
        for (int j = 0; j < 8; ++j) s[j] = ep[i + j];
        float ee[8];
        float4 ff[8];
#pragma unroll
        for (int j = 0; j < 8; ++j) {
            ee[j] = el[s[j]];
            ff[j] = *((const float4*)(fb + (size_t)s[j] * 16));
        }
#pragma unroll
        for (int j = 0; j < 8; ++j) {
            float v = ee[j] + er_n;
            v = v > 0.f ? v : NEG_SLOPE * v;
            float ex = __expf(v);
            acc.x += ex * ff[j].x; acc.y += ex * ff[j].y;
            acc.z += ex * ff[j].z; acc.w += ex * ff[j].w;
            sumex += ex;
        }
    }
    for (; i + 4 <= cnt; i += 4) {
        int s[4];
#pragma unroll
        for (int j = 0; j < 4; ++j) s[j] = ep[i + j];
        float ee[4];
        float4 ff[4];
#pragma unroll
        for (int j = 0; j < 4; ++j) {
            ee[j] = el[s[j]];
            ff[j] = *((const float4*)(fb + (size_t)s[j] * 16));
        }
#pragma unroll
        for (int j = 0; j < 4; ++j) {
            float v = ee[j] + er_n;
            v = v > 0.f ? v : NEG_SLOPE * v;
            float ex = __expf(v);
            acc.x += ex * ff[j].x; acc.y += ex * ff[j].y;
            acc.z += ex * ff[j].z; acc.w += ex * ff[j].w;
            sumex += ex;
        }
    }
    for (; i < cnt; ++i) {
        int s = ep[i];
        float v = el[s] + er_n;
        v = v > 0.f ? v : NEG_SLOPE * v;
        float ex = __expf(v);
        float4 f = *((const float4*)(fb + (size_t)s * 16));
        acc.x += ex * f.x; acc.y += ex * f.y;
        acc.z += ex * f.z; acc.w += ex * f.w;
        sumex += ex;
    }
    float inv = 1.f / ((sumex == 0.f) ? 1.f : sumex);
    float4 bb = *((const float4*)(b + d4 * 4));
    float4 o;
    o.x = acc.x * inv + bb.x;
    o.y = acc.y * inv + bb.y;
    o.z = acc.z * inv + bb.z;
    o.w = acc.w * inv + bb.w;
    *((float4*)(outp + (size_t)node * 16 + d4 * 4)) = o;
}

extern "C" void kernel_launch(void* const* d_in, const int* in_sizes, int n_in,
                              void* d_out, int out_size, void* d_ws, size_t ws_size,
                              hipStream_t stream) {
    const float* x   = (const float*)d_in[0];
    const int*   src = (const int*)d_in[1];
    const int*   dst = (const int*)d_in[2];
    const float* W1  = (const float*)d_in[3];
    const float* al1 = (const float*)d_in[4];
    const float* ar1 = (const float*)d_in[5];
    const float* b1  = (const float*)d_in[6];
    const float* W2  = (const float*)d_in[7];
    const float* al2 = (const float*)d_in[8];
    const float* ar2 = (const float*)d_in[9];
    const float* b2  = (const float*)d_in[10];

    const int E = in_sizes[1];
    const int N = in_sizes[0] / 128;
    const int H1 = 4, D1 = 32, C1 = 128;
    const int D2 = 16;
    const int NB = (N + GSZ - 1) / GSZ;
    const int NCH = (E + CHUNK - 1) / CHUNK;

    char* p = (char*)d_ws;
    auto alloc_f = [&](size_t n) { float* q = (float*)p; p += n * sizeof(float); return q; };
    auto alloc_i = [&](size_t n) { int* q = (int*)p; p += n * sizeof(int); return q; };

    __hip_bfloat16* feat1b = (__hip_bfloat16*)p; p += (size_t)N * C1 * sizeof(__hip_bfloat16);
    float* el1   = alloc_f((size_t)N * H1);
    float* er1   = alloc_f((size_t)N * H1);
    float* hbuf  = alloc_f((size_t)N * D1);
    float* feat2 = alloc_f((size_t)N * D2);
    float* el2   = alloc_f(N);
    float* er2   = alloc_f(N);
    int* deg     = alloc_i(N);
    int* rowptr  = alloc_i(N);
    int* esrc    = alloc_i(E);
    int* gcursor = alloc_i(NB);
    unsigned* inter = (unsigned*)alloc_i((size_t)NB * CHUNK);

    const int TB = 256;
    auto blocks = [&](long long n) { return (int)((n + TB - 1) / TB); };

    hipMemsetAsync(gcursor, 0, (size_t)NB * sizeof(int), stream);

    // fused: coarse bucket-scatter (NCH blocks) || gemm1+el/er (rest)
    k1_fused<<<NCH + (N + 63) / 64, TB, 0, stream>>>(
        src, dst, gcursor, inter, NB, E, NCH,
        x, W1, al1, ar1, feat1b, el1, er1, N);

    fine_scatter<<<NB, TB, 0, stream>>>(inter, gcursor, deg, rowptr, esrc, N, NB);

    pull1_kernel<<<blocks((long long)N * 32), TB, 0, stream>>>(
        rowptr, deg, esrc, el1, er1, feat1b, b1, hbuf, N);

    gemm2_fused<<<blocks((long long)N * D2), TB, 0, stream>>>(hbuf, W2, al2, ar2,
                                                              feat2, el2, er2, N);
    pull2_kernel<<<blocks((long long)N * 4), TB, 0, stream>>>(
        rowptr, deg, esrc, el2, er2, feat2, b2, (float*)d_out, N);
}

// Round 9
// 302.960 us; speedup vs baseline: 1.4148x; 1.4148x over previous
//
#include <hip/hip_runtime.h>
#include <hip/hip_bf16.h>

#define NEG_SLOPE 0.2f
#define G_SHIFT 7
#define GSZ 128          // nodes per bucket
#define CHUNK 4096       // edges per coarse block; also per-bucket region capacity

// ---------- layer-1 GEMM (K=C=128) + fused el/er epilogue, bf16 feat out ----
__global__ __launch_bounds__(256) void gemm1_fused(
    const float* __restrict__ x, const float* __restrict__ W,
    const float* __restrict__ al, const float* __restrict__ ar,
    __hip_bfloat16* __restrict__ outb, float* __restrict__ el,
    float* __restrict__ er, int N) {
    const int K = 128, C = 128, BM = 64, BK = 32;
    __shared__ float xs[BK][BM + 4];
    __shared__ float ws[BK][C];

    const int t = threadIdx.x;
    const int trow = t >> 4;
    const int tcol = t & 15;
    const int m0 = blockIdx.x * BM;

    float acc[4][8];
#pragma unroll
    for (int i = 0; i < 4; ++i)
#pragma unroll
        for (int j = 0; j < 8; ++j) acc[i][j] = 0.f;

    for (int k0 = 0; k0 < K; k0 += BK) {
        {
            const float4* W4 = (const float4*)(W + k0 * C);
#pragma unroll
            for (int r = 0; r < 4; ++r) {
                int q = t + 256 * r;
                int k = q >> 5;
                int c4 = q & 31;
                float4 v = W4[k * 32 + c4];
                *((float4*)&ws[k][c4 * 4]) = v;
            }
        }
        {
#pragma unroll
            for (int r = 0; r < 2; ++r) {
                int q = t + 256 * r;
                int m = q >> 3;
                int k4 = q & 7;
                int gm = m0 + m;
                if (gm >= N) gm = N - 1;
                float4 v = *((const float4*)(x + (size_t)gm * K + k0 + k4 * 4));
                xs[k4 * 4 + 0][m] = v.x;
                xs[k4 * 4 + 1][m] = v.y;
                xs[k4 * 4 + 2][m] = v.z;
                xs[k4 * 4 + 3][m] = v.w;
            }
        }
        __syncthreads();

#pragma unroll
        for (int k = 0; k < BK; ++k) {
            float4 a = *((const float4*)&xs[k][trow * 4]);
            float4 b0 = *((const float4*)&ws[k][tcol * 8]);
            float4 b1 = *((const float4*)&ws[k][tcol * 8 + 4]);
            float av[4] = {a.x, a.y, a.z, a.w};
            float bv[8] = {b0.x, b0.y, b0.z, b0.w, b1.x, b1.y, b1.z, b1.w};
#pragma unroll
            for (int i = 0; i < 4; ++i)
#pragma unroll
                for (int j = 0; j < 8; ++j) acc[i][j] += av[i] * bv[j];
        }
        __syncthreads();
    }

    const int h = tcol >> 2;
    const int d0 = (tcol & 3) * 8;
    float alv[8], arv[8];
#pragma unroll
    for (int j = 0; j < 8; ++j) {
        alv[j] = al[h * 32 + d0 + j];
        arv[j] = ar[h * 32 + d0 + j];
    }
#pragma unroll
    for (int i = 0; i < 4; ++i) {
        int gm = m0 + trow * 4 + i;
        if (gm < N) {
            union { __hip_bfloat16 hh[8]; uint4 u; } pk;
#pragma unroll
            for (int j = 0; j < 8; ++j) pk.hh[j] = __float2bfloat16(acc[i][j]);
            *((uint4*)(outb + (size_t)gm * C + tcol * 8)) = pk.u;
        }
        float pl = 0.f, pr = 0.f;
#pragma unroll
        for (int j = 0; j < 8; ++j) {
            pl += acc[i][j] * alv[j];
            pr += acc[i][j] * arv[j];
        }
        pl += __shfl_xor(pl, 1); pl += __shfl_xor(pl, 2);
        pr += __shfl_xor(pr, 1); pr += __shfl_xor(pr, 2);
        if ((tcol & 3) == 0 && gm < N) {
            el[gm * 4 + h] = pl;
            er[gm * 4 + h] = pr;
        }
    }
}

// ---------- coarse scatter: bucket edges, u32-packed, coalesced writes ------
__global__ __launch_bounds__(256) void coarse_scatter(
    const int* __restrict__ src, const int* __restrict__ dst,
    int* __restrict__ gcursor, unsigned* __restrict__ inter, int NB, int E) {
    __shared__ int hist[800];
    __shared__ int lbase[800];
    __shared__ int gbase[800];
    __shared__ unsigned stage[CHUNK];
    __shared__ unsigned short bstage[CHUNK];

    const int tid = threadIdx.x;
    const int e0 = blockIdx.x * CHUNK;
    const int cnt = min(CHUNK, E - e0);

    for (int i = tid; i < NB; i += 256) hist[i] = 0;
    __syncthreads();

    unsigned pk[16];
    int bb[16];
#pragma unroll
    for (int r = 0; r < 16; ++r) {
        int idx = tid + r * 256;
        if (idx < cnt) {
            int s = src[e0 + idx];
            int d = dst[e0 + idx];
            pk[r] = ((unsigned)s << G_SHIFT) | (unsigned)(d & (GSZ - 1));
            bb[r] = d >> G_SHIFT;
            atomicAdd(&hist[bb[r]], 1);
        }
    }
    __syncthreads();
    if (tid < 64) {
        int carry = 0;
        for (int i = 0; i < NB; i += 64) {
            int v = (i + tid < NB) ? hist[i + tid] : 0;
            int xv = v;
            for (int o = 1; o < 64; o <<= 1) {
                int tt = __shfl_up(xv, o, 64);
                if (tid >= o) xv += tt;
            }
            if (i + tid < NB) lbase[i + tid] = carry + xv - v;
            carry += __shfl(xv, 63, 64);
        }
    }
    __syncthreads();
    for (int i = tid; i < NB; i += 256) {
        int hh = hist[i];
        gbase[i] = (hh > 0) ? (i * CHUNK + atomicAdd(&gcursor[i], hh)) : 0;
    }
    __syncthreads();
    for (int i = tid; i < NB; i += 256) hist[i] = 0;
    __syncthreads();
#pragma unroll
    for (int r = 0; r < 16; ++r) {
        int idx = tid + r * 256;
        if (idx < cnt) {
            int b = bb[r];
            int rk = atomicAdd(&hist[b], 1);
            int pos = lbase[b] + rk;
            stage[pos] = pk[r];
            bstage[pos] = (unsigned short)b;
        }
    }
    __syncthreads();
#pragma unroll
    for (int r = 0; r < 16; ++r) {
        int idx = tid + r * 256;
        if (idx < cnt) {
            int b = (int)bstage[idx];
            inter[gbase[b] + (idx - lbase[b])] = stage[idx];
        }
    }
}

// ---------- fine scatter: per-bucket CSR finalize (self-computed base) ------
__global__ __launch_bounds__(256) void fine_scatter(
    const unsigned* __restrict__ inter, const int* __restrict__ gcursor,
    int* __restrict__ deg, int* __restrict__ rowptr, int* __restrict__ esrc,
    int N, int NB) {
    __shared__ int h[GSZ];
    __shared__ int lb[GSZ];
    __shared__ int stage[CHUNK];
    __shared__ int redsum[256];
    const int b = blockIdx.x;
    const int tid = threadIdx.x;
    const int cnt = gcursor[b];
    const unsigned* ep = inter + (size_t)b * CHUNK;

    // bucket base = sum gcursor[0..b)
    {
        int s = 0;
        for (int i = tid; i < b; i += 256) s += gcursor[i];
        redsum[tid] = s;
        __syncthreads();
        for (int o = 128; o > 0; o >>= 1) {
            if (tid < o) redsum[tid] += redsum[tid + o];
            __syncthreads();
        }
    }
    const int base = redsum[0];

    if (tid < GSZ) h[tid] = 0;
    __syncthreads();

    int ss[16];
    unsigned char ln[16];
    int nr = 0;
    for (int idx = tid; idx < cnt; idx += 256) {
        unsigned ed = ep[idx];
        ss[nr] = (int)(ed >> G_SHIFT);
        int l = (int)(ed & (GSZ - 1));
        ln[nr++] = (unsigned char)l;
        atomicAdd(&h[l], 1);
    }
    __syncthreads();
    if (tid < 64) {
        int carry = 0;
        for (int i = 0; i < GSZ; i += 64) {
            int v = h[i + tid];
            int xv = v;
            for (int o = 1; o < 64; o <<= 1) {
                int tt = __shfl_up(xv, o, 64);
                if (tid >= o) xv += tt;
            }
            lb[i + tid] = carry + xv - v;
            carry += __shfl(xv, 63, 64);
        }
    }
    __syncthreads();
    if (tid < GSZ) {
        int node = b * GSZ + tid;
        if (node < N) {
            deg[node] = h[tid];
            rowptr[node] = base + lb[tid];
        }
        h[tid] = 0;
    }
    __syncthreads();
    for (int r = 0; r < nr; ++r) {
        int l = ln[r];
        int rk = atomicAdd(&h[l], 1);
        stage[lb[l] + rk] = ss[r];
    }
    __syncthreads();
    for (int idx = tid; idx < cnt; idx += 256) esrc[base + idx] = stage[idx];
}

// ---------- layer-1 pull: 16 lanes/node, 4 heads, 16B bf16 loads, 8x MLP ----
__global__ __launch_bounds__(256) void pull1_kernel(
    const int* __restrict__ rowptr, const int* __restrict__ deg,
    const int* __restrict__ esrc, const float* __restrict__ el,
    const float* __restrict__ er, const __hip_bfloat16* __restrict__ featb,
    const float* __restrict__ b, float* __restrict__ hbuf, int N) {
    int tid = blockIdx.x * 256 + threadIdx.x;
    int node = tid >> 4;
    int lane = threadIdx.x & 15;
    int h = lane >> 2;           // head 0..3
    int d8 = lane & 3;           // 8-dim chunk 0..3
    if (node >= N) return;

    int start = rowptr[node];
    int cnt = deg[node];
    float er_nh = er[node * 4 + h];
    const int* ep = esrc + start;
    const unsigned short* fb = (const unsigned short*)featb + h * 32 + d8 * 8;

    float acc[8];
#pragma unroll
    for (int k = 0; k < 8; ++k) acc[k] = 0.f;
    float sumex = 0.f;

#define CONSUME(EE, UU)                                                    \
    {                                                                      \
        float v = (EE) + er_nh;                                            \
        v = v > 0.f ? v : NEG_SLOPE * v;                                   \
        float ex = __expf(v);                                              \
        acc[0] += ex * __uint_as_float((UU).x << 16);                      \
        acc[1] += ex * __uint_as_float((UU).x & 0xffff0000u);              \
        acc[2] += ex * __uint_as_float((UU).y << 16);                      \
        acc[3] += ex * __uint_as_float((UU).y & 0xffff0000u);              \
        acc[4] += ex * __uint_as_float((UU).z << 16);                      \
        acc[5] += ex * __uint_as_float((UU).z & 0xffff0000u);              \
        acc[6] += ex * __uint_as_float((UU).w << 16);                      \
        acc[7] += ex * __uint_as_float((UU).w & 0xffff0000u);              \
        sumex += ex;                                                       \
    }

    int i = 0;
    for (; i + 8 <= cnt; i += 8) {
        int s[8];
#pragma unroll
        for (int j = 0; j < 8; ++j) s[j] = ep[i + j];
        float ee[8];
        uint4 uu[8];
#pragma unroll
        for (int j = 0; j < 8; ++j) {
            ee[j] = el[s[j] * 4 + h];
            uu[j] = *((const uint4*)(fb + (size_t)s[j] * 128));
        }
#pragma unroll
        for (int j = 0; j < 8; ++j) CONSUME(ee[j], uu[j]);
    }
    for (; i + 4 <= cnt; i += 4) {
        int s[4];
#pragma unroll
        for (int j = 0; j < 4; ++j) s[j] = ep[i + j];
        float ee[4];
        uint4 uu[4];
#pragma unroll
        for (int j = 0; j < 4; ++j) {
            ee[j] = el[s[j] * 4 + h];
            uu[j] = *((const uint4*)(fb + (size_t)s[j] * 128));
        }
#pragma unroll
        for (int j = 0; j < 4; ++j) CONSUME(ee[j], uu[j]);
    }
    for (; i < cnt; ++i) {
        int s = ep[i];
        float ee = el[s * 4 + h];
        uint4 uu = *((const uint4*)(fb + (size_t)s * 128));
        CONSUME(ee, uu);
    }
#undef CONSUME

    float inv = 1.f / ((sumex == 0.f) ? 1.f : sumex);
    const float* bp = b + h * 32 + d8 * 8;
    float o[8];
#pragma unroll
    for (int k = 0; k < 8; ++k) o[k] = acc[k] * inv + bp[k];
    // mean over heads: lanes differing in bits 2,3 of the 16-lane group
#pragma unroll
    for (int k = 0; k < 8; ++k) {
        o[k] += __shfl_xor(o[k], 4);
        o[k] += __shfl_xor(o[k], 8);
    }
    if (h == 0) {
        float4 o0, o1;
        o0.x = fmaxf(o[0] * 0.25f, 0.f);
        o0.y = fmaxf(o[1] * 0.25f, 0.f);
        o0.z = fmaxf(o[2] * 0.25f, 0.f);
        o0.w = fmaxf(o[3] * 0.25f, 0.f);
        o1.x = fmaxf(o[4] * 0.25f, 0.f);
        o1.y = fmaxf(o[5] * 0.25f, 0.f);
        o1.z = fmaxf(o[6] * 0.25f, 0.f);
        o1.w = fmaxf(o[7] * 0.25f, 0.f);
        float* hp = hbuf + (size_t)node * 32 + d8 * 8;
        *((float4*)hp) = o0;
        *((float4*)(hp + 4)) = o1;
    }
}

// ---------- layer-2 GEMM (K=32, C=16) + fused el/er (H=1) ----------
__global__ __launch_bounds__(256) void gemm2_fused(
    const float* __restrict__ x, const float* __restrict__ W,
    const float* __restrict__ al, const float* __restrict__ ar,
    float* __restrict__ out, float* __restrict__ el, float* __restrict__ er,
    int N) {
    const int K = 32, C = 16;
    int idx = blockIdx.x * blockDim.x + threadIdx.x;
    if (idx >= N * C) return;
    int n = idx / C, c = idx % C;
    const float* xr = x + (size_t)n * K;
    float acc = 0.f;
#pragma unroll
    for (int k = 0; k < K; ++k) acc += xr[k] * W[k * C + c];
    out[idx] = acc;
    float pl = acc * al[c];
    float pr = acc * ar[c];
    pl += __shfl_xor(pl, 1); pl += __shfl_xor(pl, 2);
    pl += __shfl_xor(pl, 4); pl += __shfl_xor(pl, 8);
    pr += __shfl_xor(pr, 1); pr += __shfl_xor(pr, 2);
    pr += __shfl_xor(pr, 4); pr += __shfl_xor(pr, 8);
    if (c == 0) {
        el[n] = pl;
        er[n] = pr;
    }
}

// ---------- layer-2 pull: 4 lanes/node (H=1, D=16), fp32 feat, 8x MLP -------
__global__ __launch_bounds__(256) void pull2_kernel(
    const int* __restrict__ rowptr, const int* __restrict__ deg,
    const int* __restrict__ esrc, const float* __restrict__ el,
    const float* __restrict__ er, const float* __restrict__ feat,
    const float* __restrict__ b, float* __restrict__ outp, int N) {
    int tid = blockIdx.x * 256 + threadIdx.x;
    int node = tid >> 2;
    int d4 = threadIdx.x & 3;
    if (node >= N) return;

    int start = rowptr[node];
    int cnt = deg[node];
    float er_n = er[node];
    const int* ep = esrc + start;
    const float* fb = feat + d4 * 4;

    float4 acc = make_float4(0.f, 0.f, 0.f, 0.f);
    float sumex = 0.f;
    int i = 0;
    for (; i + 8 <= cnt; i += 8) {
        int s[8];
#pragma unroll
        for (int j = 0; j < 8; ++j) s[j] = ep[i + j];
        float ee[8];
        float4 ff[8];
#pragma unroll
        for (int j = 0; j < 8; ++j) {
            ee[j] = el[s[j]];
            ff[j] = *((const float4*)(fb + (size_t)s[j] * 16));
        }
#pragma unroll
        for (int j = 0; j < 8; ++j) {
            float v = ee[j] + er_n;
            v = v > 0.f ? v : NEG_SLOPE * v;
            float ex = __expf(v);
            acc.x += ex * ff[j].x; acc.y += ex * ff[j].y;
            acc.z += ex * ff[j].z; acc.w += ex * ff[j].w;
            sumex += ex;
        }
    }
    for (; i + 4 <= cnt; i += 4) {
        int s[4];
#pragma unroll
        for (int j = 0; j < 4; ++j) s[j] = ep[i + j];
        float ee[4];
        float4 ff[4];
#pragma unroll
        for (int j = 0; j < 4; ++j) {
            ee[j] = el[s[j]];
            ff[j] = *((const float4*)(fb + (size_t)s[j] * 16));
        }
#pragma unroll
        for (int j = 0; j < 4; ++j) {
            float v = ee[j] + er_n;
            v = v > 0.f ? v : NEG_SLOPE * v;
            float ex = __expf(v);
            acc.x += ex * ff[j].x; acc.y += ex * ff[j].y;
            acc.z += ex * ff[j].z; acc.w += ex * ff[j].w;
            sumex += ex;
        }
    }
    for (; i < cnt; ++i) {
        int s = ep[i];
        float v = el[s] + er_n;
        v = v > 0.f ? v : NEG_SLOPE * v;
        float ex = __expf(v);
        float4 f = *((const float4*)(fb + (size_t)s * 16));
        acc.x += ex * f.x; acc.y += ex * f.y;
        acc.z += ex * f.z; acc.w += ex * f.w;
        sumex += ex;
    }
    float inv = 1.f / ((sumex == 0.f) ? 1.f : sumex);
    float4 bb = *((const float4*)(b + d4 * 4));
    float4 o;
    o.x = acc.x * inv + bb.x;
    o.y = acc.y * inv + bb.y;
    o.z = acc.z * inv + bb.z;
    o.w = acc.w * inv + bb.w;
    *((float4*)(outp + (size_t)node * 16 + d4 * 4)) = o;
}

extern "C" void kernel_launch(void* const* d_in, const int* in_sizes, int n_in,
                              void* d_out, int out_size, void* d_ws, size_t ws_size,
                              hipStream_t stream) {
    const float* x   = (const float*)d_in[0];
    const int*   src = (const int*)d_in[1];
    const int*   dst = (const int*)d_in[2];
    const float* W1  = (const float*)d_in[3];
    const float* al1 = (const float*)d_in[4];
    const float* ar1 = (const float*)d_in[5];
    const float* b1  = (const float*)d_in[6];
    const float* W2  = (const float*)d_in[7];
    const float* al2 = (const float*)d_in[8];
    const float* ar2 = (const float*)d_in[9];
    const float* b2  = (const float*)d_in[10];

    const int E = in_sizes[1];
    const int N = in_sizes[0] / 128;
    const int H1 = 4, D1 = 32, C1 = 128;
    const int D2 = 16;
    const int NB = (N + GSZ - 1) / GSZ;
    const int NCH = (E + CHUNK - 1) / CHUNK;

    char* p = (char*)d_ws;
    auto alloc_f = [&](size_t n) { float* q = (float*)p; p += n * sizeof(float); return q; };
    auto alloc_i = [&](size_t n) { int* q = (int*)p; p += n * sizeof(int); return q; };

    __hip_bfloat16* feat1b = (__hip_bfloat16*)p; p += (size_t)N * C1 * sizeof(__hip_bfloat16);
    float* el1   = alloc_f((size_t)N * H1);
    float* er1   = alloc_f((size_t)N * H1);
    float* hbuf  = alloc_f((size_t)N * D1);
    float* feat2 = alloc_f((size_t)N * D2);
    float* el2   = alloc_f(N);
    float* er2   = alloc_f(N);
    int* deg     = alloc_i(N);
    int* rowptr  = alloc_i(N);
    int* esrc    = alloc_i(E);
    int* gcursor = alloc_i(NB);
    unsigned* inter = (unsigned*)alloc_i((size_t)NB * CHUNK);

    const int TB = 256;
    auto blocks = [&](long long n) { return (int)((n + TB - 1) / TB); };

    // ---- CSR build (shared by both layers) ----
    hipMemsetAsync(gcursor, 0, (size_t)NB * sizeof(int), stream);
    coarse_scatter<<<NCH, TB, 0, stream>>>(src, dst, gcursor, inter, NB, E);
    fine_scatter<<<NB, TB, 0, stream>>>(inter, gcursor, deg, rowptr, esrc, N, NB);

    // ---- layer 1 ----
    gemm1_fused<<<(N + 63) / 64, TB, 0, stream>>>(x, W1, al1, ar1, feat1b, el1, er1, N);
    pull1_kernel<<<blocks((long long)N * 16), TB, 0, stream>>>(
        rowptr, deg, esrc, el1, er1, feat1b, b1, hbuf, N);

    // ---- layer 2 ----
    gemm2_fused<<<blocks((long long)N * D2), TB, 0, stream>>>(hbuf, W2, al2, ar2,
                                                              feat2, el2, er2, N);
    pull2_kernel<<<blocks((long long)N * 4), TB, 0, stream>>>(
        rowptr, deg, esrc, el2, er2, feat2, b2, (float*)d_out, N);
}